// Round 1
// baseline (2882.997 us; speedup 1.0000x reference)
//
#include <hip/hip_runtime.h>
#include <math.h>

// ---------------------------------------------------------------------------
// GCN forward:
//   row=src, col=dst; deg[i] = 1 + #incoming(i); dinv = rsqrt(deg)
//   conv(x,W,b): h = x@W; acc[i] = sum_{e: col=i} dinv[row]*dinv[i]*h[row]
//                out[i] = relu(acc[i] + dinv[i]^2*h[i] + b)
//   head: relu(h@Wl1+bl1) @ Wl4 + bl4
// ---------------------------------------------------------------------------

__global__ void deg_kernel(const int* __restrict__ col, float* __restrict__ deg, int E) {
    int e = blockIdx.x * blockDim.x + threadIdx.x;
    if (e < E) atomicAdd(&deg[col[e]], 1.0f);
}

__global__ void dinv_kernel(float* __restrict__ deg, int N) {
    int i = blockIdx.x * blockDim.x + threadIdx.x;
    if (i < N) deg[i] = rsqrtf(deg[i] + 1.0f);   // +1 = self loop; deg>=1 always
}

// out[N,32] = x[N,16] @ W[16,32]
__global__ void gemm_16x32(const float* __restrict__ x, const float* __restrict__ W,
                           float* __restrict__ out, int N) {
    __shared__ float sW[16 * 32];
    __shared__ float sx[8][16];
    int t = threadIdx.x;
    for (int i = t; i < 16 * 32; i += 256) sW[i] = W[i];
    int nodeBase = blockIdx.x * 8;
    if (t < 128) {
        int nn = t >> 4, c = t & 15;
        int g = nodeBase + nn;
        sx[nn][c] = (g < N) ? x[g * 16 + c] : 0.0f;
    }
    __syncthreads();
    int n = t >> 5, k = t & 31;
    int g = nodeBase + n;
    if (g < N) {
        float acc = 0.0f;
#pragma unroll
        for (int c = 0; c < 16; ++c) acc += sx[n][c] * sW[c * 32 + k];
        out[g * 32 + k] = acc;
    }
}

// out[N,32] = hin[N,32] @ W[32,32]
__global__ void gemm_32x32(const float* __restrict__ hin, const float* __restrict__ W,
                           float* __restrict__ out, int N) {
    __shared__ float sW[32 * 32];
    __shared__ float sh[8][32];
    int t = threadIdx.x;
    for (int i = t; i < 32 * 32; i += 256) sW[i] = W[i];
    int nodeBase = blockIdx.x * 8;
    int n = t >> 5, k = t & 31;
    int g = nodeBase + n;
    sh[n][k] = (g < N) ? hin[g * 32 + k] : 0.0f;
    __syncthreads();
    if (g < N) {
        float acc = 0.0f;
#pragma unroll
        for (int c = 0; c < 32; ++c) acc += sh[n][c] * sW[c * 32 + k];
        out[g * 32 + k] = acc;
    }
}

// Edge-parallel scatter: 8 threads per edge, float4 per thread (32 channels).
__global__ void scatter_kernel(const int* __restrict__ row, const int* __restrict__ col,
                               const float* __restrict__ dinv, const float* __restrict__ h,
                               float* __restrict__ acc, int E) {
    int tt = blockIdx.x * blockDim.x + threadIdx.x;
    int e = tt >> 3;
    if (e >= E) return;
    int q = tt & 7;
    int r = row[e], c = col[e];
    float nrm = dinv[r] * dinv[c];
    const float4 hv = *(const float4*)(h + (size_t)r * 32 + q * 4);
    float* dst = acc + (size_t)c * 32 + q * 4;
    atomicAdd(dst + 0, nrm * hv.x);
    atomicAdd(dst + 1, nrm * hv.y);
    atomicAdd(dst + 2, nrm * hv.z);
    atomicAdd(dst + 3, nrm * hv.w);
}

// acc := relu(acc + dinv^2 * hpre + b)   (elementwise, in place on acc)
__global__ void finalize_relu(float* __restrict__ acc, const float* __restrict__ hpre,
                              const float* __restrict__ dinv, const float* __restrict__ b,
                              int N) {
    int t = blockIdx.x * blockDim.x + threadIdx.x;
    if (t >= N * 32) return;
    int i = t >> 5, k = t & 31;
    float di = dinv[i];
    float v = acc[t] + di * di * hpre[t] + b[k];
    acc[t] = fmaxf(v, 0.0f);
}

// Fused: h2 = relu(acc2 + dinv^2*hpre2 + b2); h3 = relu(h2@Wl1+bl1); out = h3@Wl4+bl4
__global__ void final_fused(const float* __restrict__ hpre2, const float* __restrict__ acc2,
                            const float* __restrict__ dinv, const float* __restrict__ b2,
                            const float* __restrict__ Wl1, const float* __restrict__ bl1,
                            const float* __restrict__ Wl4, const float* __restrict__ bl4,
                            float* __restrict__ out, int N) {
    __shared__ float sW[32 * 32];
    __shared__ float sh[8][32];
    int t = threadIdx.x;
    for (int i = t; i < 32 * 32; i += 256) sW[i] = Wl1[i];
    int n = t >> 5, k = t & 31;
    int g = blockIdx.x * 8 + n;
    float h2 = 0.0f;
    if (g < N) {
        float di = dinv[g];
        float v = acc2[(size_t)g * 32 + k] + di * di * hpre2[(size_t)g * 32 + k] + b2[k];
        h2 = fmaxf(v, 0.0f);
    }
    sh[n][k] = h2;
    __syncthreads();
    float h3 = bl1[k];
#pragma unroll
    for (int c = 0; c < 32; ++c) h3 += sh[n][c] * sW[c * 32 + k];
    h3 = fmaxf(h3, 0.0f);
    float p = h3 * Wl4[k];
    // reduce over the 32 lanes of this node (xor masks <32 never cross halves)
    p += __shfl_xor(p, 1);
    p += __shfl_xor(p, 2);
    p += __shfl_xor(p, 4);
    p += __shfl_xor(p, 8);
    p += __shfl_xor(p, 16);
    if (g < N && k == 0) out[g] = p + bl4[0];
}

extern "C" void kernel_launch(void* const* d_in, const int* in_sizes, int n_in,
                              void* d_out, int out_size, void* d_ws, size_t ws_size,
                              hipStream_t stream) {
    const float* x   = (const float*)d_in[0];
    const int*   ei  = (const int*)d_in[1];
    const float* W1  = (const float*)d_in[2];
    const float* b1  = (const float*)d_in[3];
    const float* W2  = (const float*)d_in[4];
    const float* b2  = (const float*)d_in[5];
    const float* Wl1 = (const float*)d_in[6];
    const float* bl1 = (const float*)d_in[7];
    const float* Wl4 = (const float*)d_in[8];
    const float* bl4 = (const float*)d_in[9];
    float* out = (float*)d_out;

    const int N = in_sizes[0] / 16;
    const int E = in_sizes[1] / 2;
    const int* row = ei;        // edge_index[0] : source j
    const int* col = ei + E;    // edge_index[1] : target i

    char* ws = (char*)d_ws;
    size_t offDinv = 0;
    size_t offA = ((size_t)N * 4 + 511) & ~(size_t)511;       // h_pre buffer
    size_t offB = offA + (size_t)N * 32 * 4;                  // acc / h buffer
    float* dinv = (float*)(ws + offDinv);
    float* bufA = (float*)(ws + offA);
    float* bufB = (float*)(ws + offB);

    const int BLK = 256;
    int gridE  = (E + BLK - 1) / BLK;
    int gridN  = (N + BLK - 1) / BLK;
    int gridN8 = (N + 7) / 8;
    int gridNK = (N * 32 + BLK - 1) / BLK;
    int gridS  = (E * 8 + BLK - 1) / BLK;

    // degrees -> dinv
    hipMemsetAsync(dinv, 0, (size_t)N * 4, stream);
    deg_kernel<<<gridE, BLK, 0, stream>>>(col, dinv, E);
    dinv_kernel<<<gridN, BLK, 0, stream>>>(dinv, N);

    // conv1
    gemm_16x32<<<gridN8, BLK, 0, stream>>>(x, W1, bufA, N);
    hipMemsetAsync(bufB, 0, (size_t)N * 32 * 4, stream);
    scatter_kernel<<<gridS, BLK, 0, stream>>>(row, col, dinv, bufA, bufB, E);
    finalize_relu<<<gridNK, BLK, 0, stream>>>(bufB, bufA, dinv, b1, N);   // bufB = h1

    // conv2
    gemm_32x32<<<gridN8, BLK, 0, stream>>>(bufB, W2, bufA, N);            // bufA = hpre2
    hipMemsetAsync(bufB, 0, (size_t)N * 32 * 4, stream);
    scatter_kernel<<<gridS, BLK, 0, stream>>>(row, col, dinv, bufA, bufB, E);

    // finalize conv2 + MLP head, fused
    final_fused<<<gridN8, BLK, 0, stream>>>(bufA, bufB, dinv, b2,
                                            Wl1, bl1, Wl4, bl4, out, N);
}

// Round 2
// 650.485 us; speedup vs baseline: 4.4321x; 4.4321x over previous
//
#include <hip/hip_runtime.h>
#include <math.h>

// ---------------------------------------------------------------------------
// GCN forward, CSR gather-side aggregation (no float atomics).
//   counts[i] = #incoming(i); dinv = rsqrt(counts+1)  (self loop)
//   CSR: rowPtr (exclusive scan of counts), srt[e]=src sorted by dst,
//        nrm[e]=dinv[src]*dinv[dst]
//   conv(h,b): out[i] = relu( sum_e nrm[e]*h[srt[e]] + dinv[i]^2*h[i] + b )
//   head: relu(h2@Wl1+bl1) @ Wl4 + bl4
// ---------------------------------------------------------------------------

__global__ void count_kernel(const int* __restrict__ col, int* __restrict__ counts, int E) {
    int e = blockIdx.x * blockDim.x + threadIdx.x;
    if (e < E) atomicAdd(&counts[col[e]], 1);
}

// Per-block inclusive scan (Hillis-Steele) -> exclusive out + block totals.
__global__ void scan_block(const int* __restrict__ counts, int* __restrict__ rowPtr,
                           int* __restrict__ blockSums, int N) {
    __shared__ int s[256];
    int i = blockIdx.x * 256 + threadIdx.x;
    int v = (i < N) ? counts[i] : 0;
    s[threadIdx.x] = v;
    __syncthreads();
    for (int off = 1; off < 256; off <<= 1) {
        int t = (threadIdx.x >= off) ? s[threadIdx.x - off] : 0;
        __syncthreads();
        s[threadIdx.x] += t;
        __syncthreads();
    }
    if (i < N) rowPtr[i] = s[threadIdx.x] - v;          // exclusive
    if (threadIdx.x == 255) blockSums[blockIdx.x] = s[255];
}

// Single-block exclusive scan of block sums (nB <= 512).
__global__ void scan_sums(int* __restrict__ blockSums, int nB) {
    __shared__ int s[512];
    int t = threadIdx.x;
    int v = (t < nB) ? blockSums[t] : 0;
    s[t] = v;
    __syncthreads();
    for (int off = 1; off < 512; off <<= 1) {
        int u = (t >= off) ? s[t - off] : 0;
        __syncthreads();
        s[t] += u;
        __syncthreads();
    }
    if (t < nB) blockSums[t] = s[t] - v;                // exclusive
}

__global__ void add_offsets(int* __restrict__ rowPtr, int* __restrict__ cursor,
                            const int* __restrict__ blockSums, int N, int E) {
    int i = blockIdx.x * blockDim.x + threadIdx.x;
    if (i < N) {
        int v = rowPtr[i] + blockSums[i >> 8];
        rowPtr[i] = v;
        cursor[i] = v;
    }
    if (i == 0) rowPtr[N] = E;
}

__global__ void dinv_kernel(const int* __restrict__ counts, float* __restrict__ dinv, int N) {
    int i = blockIdx.x * blockDim.x + threadIdx.x;
    if (i < N) dinv[i] = rsqrtf((float)counts[i] + 1.0f);
}

__global__ void fill_kernel(const int* __restrict__ row, const int* __restrict__ col,
                            const float* __restrict__ dinv, int* __restrict__ cursor,
                            int* __restrict__ srt, float* __restrict__ nrm, int E) {
    int e = blockIdx.x * blockDim.x + threadIdx.x;
    if (e >= E) return;
    int r = row[e], c = col[e];
    int pos = atomicAdd(&cursor[c], 1);
    srt[pos] = r;
    nrm[pos] = dinv[r] * dinv[c];
}

// out[N,32] = x[N,16] @ W[16,32]
__global__ void gemm_16x32(const float* __restrict__ x, const float* __restrict__ W,
                           float* __restrict__ out, int N) {
    __shared__ float sW[16 * 32];
    __shared__ float sx[8][16];
    int t = threadIdx.x;
    for (int i = t; i < 16 * 32; i += 256) sW[i] = W[i];
    int nodeBase = blockIdx.x * 8;
    if (t < 128) {
        int nn = t >> 4, c = t & 15;
        int g = nodeBase + nn;
        sx[nn][c] = (g < N) ? x[g * 16 + c] : 0.0f;
    }
    __syncthreads();
    int n = t >> 5, k = t & 31;
    int g = nodeBase + n;
    if (g < N) {
        float acc = 0.0f;
#pragma unroll
        for (int c = 0; c < 16; ++c) acc += sx[n][c] * sW[c * 32 + k];
        out[g * 32 + k] = acc;
    }
}

// out[N,32] = hin[N,32] @ W[32,32]
__global__ void gemm_32x32(const float* __restrict__ hin, const float* __restrict__ W,
                           float* __restrict__ out, int N) {
    __shared__ float sW[32 * 32];
    __shared__ float sh[8][32];
    int t = threadIdx.x;
    for (int i = t; i < 32 * 32; i += 256) sW[i] = W[i];
    int nodeBase = blockIdx.x * 8;
    int n = t >> 5, k = t & 31;
    int g = nodeBase + n;
    sh[n][k] = (g < N) ? hin[g * 32 + k] : 0.0f;
    __syncthreads();
    if (g < N) {
        float acc = 0.0f;
#pragma unroll
        for (int c = 0; c < 32; ++c) acc += sh[n][c] * sW[c * 32 + k];
        out[g * 32 + k] = acc;
    }
}

// Gather-side aggregation, fused with self-loop + bias + ReLU.
// 8 threads per dst node, float4 per thread (32 channels).
__global__ void gather_agg(const int* __restrict__ rowPtr, const int* __restrict__ srt,
                           const float* __restrict__ nrm, const float* __restrict__ h,
                           const float* __restrict__ dinv, const float* __restrict__ b,
                           float* __restrict__ outh, int N) {
    int tt = blockIdx.x * blockDim.x + threadIdx.x;
    int node = tt >> 3;
    if (node >= N) return;
    int q = tt & 7;
    int beg = rowPtr[node], end = rowPtr[node + 1];
    float ax = 0.0f, ay = 0.0f, az = 0.0f, aw = 0.0f;
    for (int e = beg; e < end; ++e) {
        int s = srt[e];
        float w = nrm[e];
        const float4 hv = *(const float4*)(h + (size_t)s * 32 + q * 4);
        ax += w * hv.x; ay += w * hv.y; az += w * hv.z; aw += w * hv.w;
    }
    float di = dinv[node];
    float d2 = di * di;
    const float4 hp = *(const float4*)(h + (size_t)node * 32 + q * 4);
    const float4 bv = *(const float4*)(b + q * 4);
    float4 r;
    r.x = fmaxf(ax + d2 * hp.x + bv.x, 0.0f);
    r.y = fmaxf(ay + d2 * hp.y + bv.y, 0.0f);
    r.z = fmaxf(az + d2 * hp.z + bv.z, 0.0f);
    r.w = fmaxf(aw + d2 * hp.w + bv.w, 0.0f);
    *(float4*)(outh + (size_t)node * 32 + q * 4) = r;
}

// MLP head: h3 = relu(h2@Wl1+bl1); out = h3@Wl4+bl4
__global__ void mlp_head(const float* __restrict__ h2, const float* __restrict__ Wl1,
                         const float* __restrict__ bl1, const float* __restrict__ Wl4,
                         const float* __restrict__ bl4, float* __restrict__ out, int N) {
    __shared__ float sW[32 * 32];
    __shared__ float sh[8][32];
    int t = threadIdx.x;
    for (int i = t; i < 32 * 32; i += 256) sW[i] = Wl1[i];
    int n = t >> 5, k = t & 31;
    int g = blockIdx.x * 8 + n;
    sh[n][k] = (g < N) ? h2[(size_t)g * 32 + k] : 0.0f;
    __syncthreads();
    float h3 = bl1[k];
#pragma unroll
    for (int c = 0; c < 32; ++c) h3 += sh[n][c] * sW[c * 32 + k];
    h3 = fmaxf(h3, 0.0f);
    float p = h3 * Wl4[k];
    p += __shfl_xor(p, 1);
    p += __shfl_xor(p, 2);
    p += __shfl_xor(p, 4);
    p += __shfl_xor(p, 8);
    p += __shfl_xor(p, 16);
    if (g < N && k == 0) out[g] = p + bl4[0];
}

extern "C" void kernel_launch(void* const* d_in, const int* in_sizes, int n_in,
                              void* d_out, int out_size, void* d_ws, size_t ws_size,
                              hipStream_t stream) {
    const float* x   = (const float*)d_in[0];
    const int*   ei  = (const int*)d_in[1];
    const float* W1  = (const float*)d_in[2];
    const float* b1  = (const float*)d_in[3];
    const float* W2  = (const float*)d_in[4];
    const float* b2  = (const float*)d_in[5];
    const float* Wl1 = (const float*)d_in[6];
    const float* bl1 = (const float*)d_in[7];
    const float* Wl4 = (const float*)d_in[8];
    const float* bl4 = (const float*)d_in[9];
    float* out = (float*)d_out;

    const int N = in_sizes[0] / 16;
    const int E = in_sizes[1] / 2;
    const int* row = ei;        // edge_index[0] : source j
    const int* col = ei + E;    // edge_index[1] : target i

    // workspace layout (512B aligned)
    char* ws = (char*)d_ws;
    auto align = [](size_t v) { return (v + 511) & ~(size_t)511; };
    size_t o = 0;
    int*   counts    = (int*)(ws + o);  o = align(o + (size_t)N * 4);
    int*   rowPtr    = (int*)(ws + o);  o = align(o + (size_t)(N + 1) * 4);
    int*   cursor    = (int*)(ws + o);  o = align(o + (size_t)N * 4);
    int*   blockSums = (int*)(ws + o);  o = align(o + 512 * 4);
    float* dinv      = (float*)(ws + o); o = align(o + (size_t)N * 4);
    int*   srt       = (int*)(ws + o);  o = align(o + (size_t)E * 4);
    float* nrm       = (float*)(ws + o); o = align(o + (size_t)E * 4);
    float* bufA      = (float*)(ws + o); o = align(o + (size_t)N * 32 * 4);
    float* bufB      = (float*)(ws + o); o = align(o + (size_t)N * 32 * 4);

    const int BLK = 256;
    int gridE  = (E + BLK - 1) / BLK;
    int gridN  = (N + BLK - 1) / BLK;
    int gridN8 = (N + 7) / 8;
    int gridG  = (N * 8 + BLK - 1) / BLK;
    int nB     = (N + 255) / 256;

    // --- CSR build ---
    hipMemsetAsync(counts, 0, (size_t)N * 4, stream);
    count_kernel<<<gridE, BLK, 0, stream>>>(col, counts, E);
    scan_block<<<nB, 256, 0, stream>>>(counts, rowPtr, blockSums, N);
    scan_sums<<<1, 512, 0, stream>>>(blockSums, nB);
    add_offsets<<<gridN, BLK, 0, stream>>>(rowPtr, cursor, blockSums, N, E);
    dinv_kernel<<<gridN, BLK, 0, stream>>>(counts, dinv, N);
    fill_kernel<<<gridE, BLK, 0, stream>>>(row, col, dinv, cursor, srt, nrm, E);

    // --- conv1 ---
    gemm_16x32<<<gridN8, BLK, 0, stream>>>(x, W1, bufA, N);
    gather_agg<<<gridG, BLK, 0, stream>>>(rowPtr, srt, nrm, bufA, dinv, b1, bufB, N);

    // --- conv2 ---
    gemm_32x32<<<gridN8, BLK, 0, stream>>>(bufB, W2, bufA, N);
    gather_agg<<<gridG, BLK, 0, stream>>>(rowPtr, srt, nrm, bufA, dinv, b2, bufB, N);

    // --- MLP head ---
    mlp_head<<<gridN8, BLK, 0, stream>>>(bufB, Wl1, bl1, Wl4, bl4, out, N);
}